// Round 2
// baseline (583.257 us; speedup 1.0000x reference)
//
#include <hip/hip_runtime.h>
#include <hip/hip_bf16.h>

#define NT 8192
#define NS 8192
#define FD 128
#define PD 128
#define KTOP 2457                      /* max(1, int(8192*0.3)) */
#define TAUINV 14.285714285714286f     /* 1/0.07 */
#define NBIN 512
#define HSIZE 65536
#define HMASK 65535
#define CAND_MAX 768

// ---------------------------------------------------------------------------
// Workspace init (replaces hipMemsetAsync; must run every call: ws is
// re-poisoned to 0xAA before each timed launch).
// ---------------------------------------------------------------------------
__global__ __launch_bounds__(256) void init_ws(float* stats, int* hkey)
{
  int i = blockIdx.x * 256 + threadIdx.x;
  if (i < 512) stats[i] = 0.f;
  if (i < HSIZE) hkey[i] = -1;
}

// ---------------------------------------------------------------------------
// Projection MLP (pre-BN): H = relu(X@W1+b1)@W2+b2, plus per-column sum/sumsq
// Block: 256 threads, 32 rows. Thread: 8 rows x 2 cols.
// ---------------------------------------------------------------------------
__global__ __launch_bounds__(256) void proj_mlp(
    const float* __restrict__ X, const float* __restrict__ W1,
    const float* __restrict__ B1, const float* __restrict__ W2,
    const float* __restrict__ B2, float* __restrict__ H,
    float* __restrict__ colsum, float* __restrict__ colsq)
{
  __shared__ __align__(16) float Xs[32][128];
  __shared__ __align__(16) float H1s[32][128];
  __shared__ float cs[128], cq[128];
  int tid = threadIdx.x;
  int r0 = blockIdx.x * 32;
  for (int i = tid; i < 32 * 32; i += 256) {          // 32 rows x 32 float4
    int r = i >> 5, q = i & 31;
    ((float4*)Xs[r])[q] = ((const float4*)(X + (size_t)(r0 + r) * FD))[q];
  }
  if (tid < 128) { cs[tid] = 0.f; cq[tid] = 0.f; }
  __syncthreads();

  int c  = (tid & 63) * 2;          // column pair
  int rg = (tid >> 6) * 8;          // row group (wave-uniform -> LDS broadcast)
  float a0[8], a1[8];
  #pragma unroll
  for (int r = 0; r < 8; ++r) { a0[r] = 0.f; a1[r] = 0.f; }
  for (int k = 0; k < FD; ++k) {
    float2 w = *(const float2*)(W1 + k * FD + c);
    #pragma unroll
    for (int r = 0; r < 8; ++r) {
      float x = Xs[rg + r][k];
      a0[r] = fmaf(x, w.x, a0[r]);
      a1[r] = fmaf(x, w.y, a1[r]);
    }
  }
  float2 b = *(const float2*)(B1 + c);
  #pragma unroll
  for (int r = 0; r < 8; ++r) {
    H1s[rg + r][c]     = fmaxf(a0[r] + b.x, 0.f);
    H1s[rg + r][c + 1] = fmaxf(a1[r] + b.y, 0.f);
  }
  __syncthreads();

  #pragma unroll
  for (int r = 0; r < 8; ++r) { a0[r] = 0.f; a1[r] = 0.f; }
  for (int k = 0; k < FD; ++k) {
    float2 w = *(const float2*)(W2 + k * PD + c);
    #pragma unroll
    for (int r = 0; r < 8; ++r) {
      float x = H1s[rg + r][k];
      a0[r] = fmaf(x, w.x, a0[r]);
      a1[r] = fmaf(x, w.y, a1[r]);
    }
  }
  b = *(const float2*)(B2 + c);
  float s0 = 0.f, s1 = 0.f, q0 = 0.f, q1 = 0.f;
  #pragma unroll
  for (int r = 0; r < 8; ++r) {
    float h0 = a0[r] + b.x, h1 = a1[r] + b.y;
    *(float2*)(H + (size_t)(r0 + rg + r) * PD + c) = make_float2(h0, h1);
    s0 += h0; s1 += h1; q0 += h0 * h0; q1 += h1 * h1;
  }
  atomicAdd(&cs[c], s0);     atomicAdd(&cs[c + 1], s1);
  atomicAdd(&cq[c], q0);     atomicAdd(&cq[c + 1], q1);
  __syncthreads();
  if (tid < 128) { atomicAdd(&colsum[tid], cs[tid]); atomicAdd(&colsq[tid], cq[tid]); }
}

// ---------------------------------------------------------------------------
// BatchNorm (stats from colsum/colsq) + row L2 normalize. 2 rows / 256-block.
// ---------------------------------------------------------------------------
__global__ __launch_bounds__(256) void bn_l2(
    const float* __restrict__ H, const float* __restrict__ colsum,
    const float* __restrict__ colsq, const float* __restrict__ gamma,
    const float* __restrict__ beta, float* __restrict__ O, float invN)
{
  __shared__ float part[2][2];
  int half = threadIdx.x >> 7;
  int c    = threadIdx.x & 127;
  int wih  = (threadIdx.x >> 6) & 1;
  size_t row = (size_t)blockIdx.x * 2 + half;
  float mu  = colsum[c] * invN;
  float var = colsq[c] * invN - mu * mu;
  float inv = rsqrtf(var + 1e-5f);
  float y = (H[row * PD + c] - mu) * inv * gamma[c] + beta[c];
  float sq = y * y;
  #pragma unroll
  for (int off = 32; off >= 1; off >>= 1) sq += __shfl_xor(sq, off, 64);
  if ((threadIdx.x & 63) == 0) part[half][wih] = sq;
  __syncthreads();
  float norm = sqrtf(part[half][0] + part[half][1]);
  O[row * PD + c] = y / norm;
}

// ---------------------------------------------------------------------------
// Coordinate hash (teacher keys unique): open addressing, 64K slots.
// ---------------------------------------------------------------------------
__device__ __forceinline__ int coord_key(int4 c) {
  return ((c.x * 64 + c.y) * 128 + c.z) * 128 + c.w;
}

__global__ __launch_bounds__(256) void hash_insert(
    const int* __restrict__ coords, int* __restrict__ hkey, int* __restrict__ hval)
{
  int t = blockIdx.x * 256 + threadIdx.x;
  if (t >= NT) return;
  int key = coord_key(((const int4*)coords)[t]);
  unsigned slot = (((unsigned)key * 2654435761u) >> 16) & HMASK;
  while (true) {
    int old = atomicCAS(&hkey[slot], -1, key);
    if (old == -1) { hval[slot] = t; break; }
    slot = (slot + 1) & HMASK;
  }
}

__global__ __launch_bounds__(256) void hash_lookup(
    const int* __restrict__ coords, const int* __restrict__ hkey,
    const int* __restrict__ hval, int* __restrict__ tidx)
{
  int s = blockIdx.x * 256 + threadIdx.x;
  if (s >= NS) return;
  int key = coord_key(((const int4*)coords)[s]);
  unsigned slot = (((unsigned)key * 2654435761u) >> 16) & HMASK;
  int res = -1;
  while (true) {
    int k = hkey[slot];
    if (k == key) { res = hval[slot]; break; }
    if (k == -1) break;
    slot = (slot + 1) & HMASK;
  }
  tidx[s] = res;
}

// ---------------------------------------------------------------------------
// SGEMM (NT): Pb[local_s][t] = dot(A[local_s,:], B[t,:]) * TAUINV.
// A is pre-offset by the batch row start. 128x128 tile, 256 threads,
// 8x8 micro-tile, KS=32. fp32 (no fp32 MFMA on CDNA4).
// ---------------------------------------------------------------------------
#define BT 128
#define KS 32
__global__ __launch_bounds__(256) void sgemm_nt(
    const float* __restrict__ A, const float* __restrict__ B, float* __restrict__ C)
{
  __shared__ __align__(16) float As[KS][BT];
  __shared__ __align__(16) float Bs[KS][BT];
  int tid = threadIdx.x;
  int tx = tid & 15, ty = tid >> 4;
  int m0 = ty * 8, n0 = tx * 8;
  int arow = blockIdx.y * BT, brow = blockIdx.x * BT;
  float acc[8][8] = {};
  for (int k0 = 0; k0 < FD; k0 += KS) {
    for (int i = tid; i < BT * (KS / 4); i += 256) {  // 1024 float4 per matrix
      int r = i >> 3, q = i & 7;
      float4 va = ((const float4*)(A + (size_t)(arow + r) * FD + k0))[q];
      float4 vb = ((const float4*)(B + (size_t)(brow + r) * FD + k0))[q];
      As[q * 4 + 0][r] = va.x; As[q * 4 + 1][r] = va.y;
      As[q * 4 + 2][r] = va.z; As[q * 4 + 3][r] = va.w;
      Bs[q * 4 + 0][r] = vb.x; Bs[q * 4 + 1][r] = vb.y;
      Bs[q * 4 + 2][r] = vb.z; Bs[q * 4 + 3][r] = vb.w;
    }
    __syncthreads();
    #pragma unroll 8
    for (int k = 0; k < KS; ++k) {
      float a[8], bb[8];
      *(float4*)&a[0]  = *(float4*)&As[k][m0];
      *(float4*)&a[4]  = *(float4*)&As[k][m0 + 4];
      *(float4*)&bb[0] = *(float4*)&Bs[k][n0];
      *(float4*)&bb[4] = *(float4*)&Bs[k][n0 + 4];
      #pragma unroll
      for (int i = 0; i < 8; ++i)
        #pragma unroll
        for (int j = 0; j < 8; ++j)
          acc[i][j] = fmaf(a[i], bb[j], acc[i][j]);
    }
    __syncthreads();
  }
  #pragma unroll
  for (int i = 0; i < 8; ++i) {
    float4 v0 = make_float4(acc[i][0] * TAUINV, acc[i][1] * TAUINV,
                            acc[i][2] * TAUINV, acc[i][3] * TAUINV);
    float4 v1 = make_float4(acc[i][4] * TAUINV, acc[i][5] * TAUINV,
                            acc[i][6] * TAUINV, acc[i][7] * TAUINV);
    float* cp = C + (size_t)(arow + m0 + i) * NT + (brow + n0);
    ((float4*)cp)[0] = v0;
    ((float4*)cp)[1] = v1;
  }
}

// ---------------------------------------------------------------------------
// Per-row exact top-k threshold + logsumexp.  One block per matched row.
// Pb holds rows [s0, s0+batch).  Exact k-th largest via iterative 512-bin
// histogram refine + O(c^2) rank select on the threshold bin's candidates;
// tie handling matches jax.lax.top_k exactly.
// ---------------------------------------------------------------------------
__global__ __launch_bounds__(256) void select_lse(
    const float* __restrict__ Pb, const int* __restrict__ tidx,
    float* __restrict__ perrow, int s0)
{
  int s = s0 + blockIdx.x;
  int ti = tidx[s];
  if (ti < 0) return;                       // unmatched: contributes 0, skip

  __shared__ __align__(16) float row[NT];
  __shared__ unsigned hist[NBIN];
  __shared__ float cand[CAND_MAX];
  __shared__ float red[4];
  __shared__ int redi[4];
  __shared__ float sh_lo[4], sh_scale[4];
  __shared__ int sh_bin[4];
  __shared__ int sh_selB, sh_jrem, sh_cntB;
  __shared__ unsigned sh_ccount;
  __shared__ float sh_M, sh_theta;

  int tid = threadIdx.x;
  int lane = tid & 63, wid = tid >> 6;
  const float* p = Pb + (size_t)blockIdx.x * NT;

  // ---- load row into LDS + row max ----
  float mx = -1e30f;
  for (int i = tid; i < NT / 4; i += 256) {
    float4 v = ((const float4*)p)[i];
    ((float4*)row)[i] = v;
    mx = fmaxf(fmaxf(mx, v.x), fmaxf(v.y, fmaxf(v.z, v.w)));
  }
  #pragma unroll
  for (int off = 32; off >= 1; off >>= 1) mx = fmaxf(mx, __shfl_xor(mx, off, 64));
  if (lane == 0) red[wid] = mx;
  __syncthreads();
  if (tid == 0) sh_M = fmaxf(fmaxf(red[0], red[1]), fmaxf(red[2], red[3]));

  // ---- histogram refinement to isolate the k-th largest ----
  int kneed = KTOP;
  float lo = -14.6f, hi = 14.6f;            // |sims| <= 1/TAU = 14.2857
  int nlev = 0, jrem = 0, cntB = 0;
  for (int level = 0; level < 4; ++level) {
    float scale = (float)NBIN / (hi - lo);
    for (int i = tid; i < NBIN; i += 256) hist[i] = 0;
    __syncthreads();
    for (int i = tid; i < NT; i += 256) {
      float v = row[i];
      bool act = true;
      for (int l = 0; l < nlev; ++l) {
        int bb = (int)((v - sh_lo[l]) * sh_scale[l]);
        bb = bb < 0 ? 0 : (bb > NBIN - 1 ? NBIN - 1 : bb);
        act = act && (bb == sh_bin[l]);
      }
      if (act) {
        int bb = (int)((v - lo) * scale);
        bb = bb < 0 ? 0 : (bb > NBIN - 1 ? NBIN - 1 : bb);
        atomicAdd(&hist[bb], 1u);
      }
    }
    __syncthreads();
    // in-place suffix sum (Hillis-Steele), 2 bins/thread
    for (int off = 1; off < NBIN; off <<= 1) {
      unsigned a0 = (tid + off < NBIN) ? hist[tid + off] : 0u;
      unsigned a1 = (tid + 256 + off < NBIN) ? hist[tid + 256 + off] : 0u;
      __syncthreads();
      hist[tid] += a0;
      hist[tid + 256] += a1;
      __syncthreads();
    }
    // find bin holding the kneed-th largest
    #pragma unroll
    for (int u = 0; u < 2; ++u) {
      int i = tid + u * 256;
      unsigned si = hist[i];
      unsigned sn = (i < NBIN - 1) ? hist[i + 1] : 0u;
      if (si >= (unsigned)kneed && sn < (unsigned)kneed) {
        sh_selB = i;
        sh_jrem = kneed - (int)sn;
        sh_cntB = (int)(si - sn);
      }
    }
    __syncthreads();
    int B = sh_selB; jrem = sh_jrem; cntB = sh_cntB;
    if (tid == 0) { sh_lo[level] = lo; sh_scale[level] = scale; sh_bin[level] = B; }
    nlev = level + 1;
    if (cntB <= CAND_MAX) break;
    float wdt = (hi - lo) * (1.0f / NBIN);
    lo = lo + (float)B * wdt;
    hi = lo + wdt;
    kneed = jrem;
    __syncthreads();
  }

  // ---- collect candidates from threshold bin ----
  if (tid == 0) sh_ccount = 0;
  __syncthreads();
  for (int i = tid; i < NT; i += 256) {
    float v = row[i];
    bool act = true;
    for (int l = 0; l < nlev; ++l) {
      int bb = (int)((v - sh_lo[l]) * sh_scale[l]);
      bb = bb < 0 ? 0 : (bb > NBIN - 1 ? NBIN - 1 : bb);
      act = act && (bb == sh_bin[l]);
    }
    if (act) {
      unsigned idx = atomicAdd(&sh_ccount, 1u);
      if (idx < CAND_MAX) cand[idx] = v;
    }
  }
  __syncthreads();
  int c = (int)sh_ccount; if (c > CAND_MAX) c = CAND_MAX;

  // ---- exact jrem-th largest among candidates (O(c^2) rank) ----
  float thl = -1e30f;
  for (int i = tid; i < c; i += 256) {
    float v = cand[i];
    int gt = 0, eq = 0;
    for (int m = 0; m < c; ++m) {
      float u = cand[m];
      gt += (u > v) ? 1 : 0;
      eq += (u == v) ? 1 : 0;
    }
    if (gt < jrem && jrem <= gt + eq) thl = v;
  }
  #pragma unroll
  for (int off = 32; off >= 1; off >>= 1) thl = fmaxf(thl, __shfl_xor(thl, off, 64));
  if (lane == 0) red[wid] = thl;
  __syncthreads();
  if (tid == 0) sh_theta = fmaxf(fmaxf(red[0], red[1]), fmaxf(red[2], red[3]));
  __syncthreads();
  float theta = sh_theta, M = sh_M;

  // ---- exp-sum over strict top + tie copies + positive term ----
  float esum = 0.f; int cgt = 0;
  for (int i = tid; i < NT; i += 256) {
    float v = row[i];
    if (v > theta) { esum += __expf(v - M); cgt++; }
  }
  #pragma unroll
  for (int off = 32; off >= 1; off >>= 1) {
    esum += __shfl_xor(esum, off, 64);
    cgt  += __shfl_xor(cgt, off, 64);
  }
  if (lane == 0) { red[wid] = esum; redi[wid] = cgt; }
  __syncthreads();
  if (tid == 0) {
    float E = red[0] + red[1] + red[2] + red[3];
    int   G = redi[0] + redi[1] + redi[2] + redi[3];
    float pos = row[ti];
    float S = E + (float)(KTOP - G) * __expf(theta - M) + __expf(pos - M);
    perrow[s] = logf(S) + M - pos;
  }
}

// ---------------------------------------------------------------------------
__global__ __launch_bounds__(256) void finalize(
    const float* __restrict__ perrow, const int* __restrict__ tidx,
    float* __restrict__ out)
{
  __shared__ float ssum[4], scnt[4];
  float s = 0.f, c = 0.f;
  for (int i = threadIdx.x; i < NS; i += 256) {
    if (tidx[i] >= 0) { s += perrow[i]; c += 1.f; }
  }
  #pragma unroll
  for (int off = 32; off >= 1; off >>= 1) {
    s += __shfl_xor(s, off, 64);
    c += __shfl_xor(c, off, 64);
  }
  int lane = threadIdx.x & 63, wid = threadIdx.x >> 6;
  if (lane == 0) { ssum[wid] = s; scnt[wid] = c; }
  __syncthreads();
  if (threadIdx.x == 0) {
    float S = ssum[0] + ssum[1] + ssum[2] + ssum[3];
    float C = scnt[0] + scnt[1] + scnt[2] + scnt[3];
    out[0] = S / fmaxf(C, 1.f);
  }
}

// ---------------------------------------------------------------------------
extern "C" void kernel_launch(void* const* d_in, const int* in_sizes, int n_in,
                              void* d_out, int out_size, void* d_ws, size_t ws_size,
                              hipStream_t stream)
{
  const float* t_feat  = (const float*)d_in[0];
  const float* s_feat  = (const float*)d_in[1];
  const float* t_w1    = (const float*)d_in[2];
  const float* t_b1    = (const float*)d_in[3];
  const float* t_w2    = (const float*)d_in[4];
  const float* t_b2    = (const float*)d_in[5];
  const float* t_gamma = (const float*)d_in[6];
  const float* t_beta  = (const float*)d_in[7];
  const float* s_w1    = (const float*)d_in[8];
  const float* s_b1    = (const float*)d_in[9];
  const float* s_w2    = (const float*)d_in[10];
  const float* s_b2    = (const float*)d_in[11];
  const float* s_gamma = (const float*)d_in[12];
  const float* s_beta  = (const float*)d_in[13];
  const int*   t_coord = (const int*)d_in[14];
  const int*   s_coord = (const int*)d_in[15];

  // ws layout (bytes) — fixed region 12.57 MB, then batched P:
  //   0        B0: Ht, later aliased as Sp   4 MB
  //   4 MB     B1: Hs                        4 MB
  //   8 MB     B2: Tp                        4 MB
  //   12 MB    stats (512 f32)               2 KB
  //   +2K      hkey   256 KB
  //   +        hval   256 KB
  //   +        tidx   32 KB
  //   +        perrow 32 KB
  //   12.57 MB Pb: BATCH x 8192 f32  (BATCH chosen from ws_size)
  char* w = (char*)d_ws;
  float* Ht     = (float*)(w + 0);
  float* Hs     = (float*)(w + 4194304);
  float* Tp     = (float*)(w + 8388608);
  float* Sp     = (float*)(w + 0);          // aliases Ht (dead after bn_l2 t)
  float* stats  = (float*)(w + 12582912);
  float* cs_t = stats, *cq_t = stats + 128, *cs_s = stats + 256, *cq_s = stats + 384;
  int*   hkey   = (int*)(w + 12584960);
  int*   hval   = (int*)(w + 12847104);
  int*   tidx   = (int*)(w + 13109248);
  float* perrow = (float*)(w + 13142016);
  float* Pb     = (float*)(w + 13174784);
  const size_t base_need = 13174784;

  // pick batch (rows of P held at once): 2048 -> 64 MB ... 256 -> 8 MB.
  // ws_size is constant across calls -> identical launch sequence every call.
  size_t avail = ws_size > base_need ? ws_size - base_need : 0;
  int batch = 2048;
  while ((size_t)batch * NT * sizeof(float) > avail && batch > 256) batch >>= 1;

  init_ws<<<HSIZE / 256, 256, 0, stream>>>(stats, hkey);

  proj_mlp<<<NT / 32, 256, 0, stream>>>(t_feat, t_w1, t_b1, t_w2, t_b2, Ht, cs_t, cq_t);
  proj_mlp<<<NS / 32, 256, 0, stream>>>(s_feat, s_w1, s_b1, s_w2, s_b2, Hs, cs_s, cq_s);
  bn_l2<<<NT / 2, 256, 0, stream>>>(Ht, cs_t, cq_t, t_gamma, t_beta, Tp, 1.f / NT);
  bn_l2<<<NS / 2, 256, 0, stream>>>(Hs, cs_s, cq_s, s_gamma, s_beta, Sp, 1.f / NS);
  hash_insert<<<NT / 256, 256, 0, stream>>>(t_coord, hkey, hval);
  hash_lookup<<<NS / 256, 256, 0, stream>>>(s_coord, hkey, hval, tidx);

  for (int b0 = 0; b0 < NS; b0 += batch) {
    dim3 g(NT / BT, batch / BT);
    sgemm_nt<<<g, 256, 0, stream>>>(Sp + (size_t)b0 * FD, Tp, Pb);
    select_lse<<<batch, 256, 0, stream>>>(Pb, tidx, perrow, b0);
  }
  finalize<<<1, 256, 0, stream>>>(perrow, tidx, (float*)d_out);
}